// Round 2
// baseline (124.805 us; speedup 1.0000x reference)
//
#include <hip/hip_runtime.h>
#include <hip/hip_bf16.h>

typedef __bf16 bf16;
typedef __attribute__((ext_vector_type(4))) __bf16 bf16x4;
typedef __attribute__((ext_vector_type(8))) __bf16 bf16x8;
typedef __attribute__((ext_vector_type(4))) float f32x4;

#define SEQ   4096
#define DIMN  1024
#define NHEAD 8
#define HD    128
#define MALL  4160   /* 4096 X rows + 64 Cp rows */
#define PENV  -10000.0f

typedef const __attribute__((address_space(1))) void gvoid_t;
typedef __attribute__((address_space(3))) void lvoid_t;

// ---------------------------------------------------------------- cvt: fp32 -> bf16, X ++ Cp
__global__ __launch_bounds__(256) void cvt_cat_kernel(
    const float* __restrict__ X, const float* __restrict__ Cp, bf16* __restrict__ A) {
  int i = blockIdx.x * 256 + threadIdx.x;
  size_t base = (size_t)i * 4;
  if (base >= (size_t)MALL * DIMN) return;
  const float* src = (base < (size_t)SEQ * DIMN) ? (X + base) : (Cp + (base - (size_t)SEQ * DIMN));
  float4 v = *(const float4*)src;
  bf16x4 o;
  o[0] = (bf16)v.x; o[1] = (bf16)v.y; o[2] = (bf16)v.z; o[3] = (bf16)v.w;
  *(bf16x4*)&A[base] = o;
}

// ---------------------------------------------------------------- cvt+transpose W[k][n] -> Wt[n][k] bf16
__global__ __launch_bounds__(256) void cvt_trans_kernel(
    const float* __restrict__ W0, const float* __restrict__ W1, const float* __restrict__ W2,
    bf16* __restrict__ Wt) {
  const float* W = (blockIdx.z == 0) ? W0 : ((blockIdx.z == 1) ? W1 : W2);
  bf16* dst = Wt + (size_t)blockIdx.z * DIMN * DIMN;
  __shared__ bf16 tile[64][72];
  int k0 = blockIdx.y * 64, n0 = blockIdx.x * 64;
  int tx = threadIdx.x & 63, ty = threadIdx.x >> 6;
#pragma unroll
  for (int r = ty; r < 64; r += 4)
    tile[tx][r] = (bf16)W[(size_t)(k0 + r) * DIMN + n0 + tx];
  __syncthreads();
#pragma unroll
  for (int r = ty; r < 64; r += 4)
    dst[(size_t)(n0 + r) * DIMN + k0 + tx] = tile[r][tx];
}

// ---------------------------------------------------------------- fused QKV GEMM (m97 structure):
// out = A @ W^T(stored [n][k]) + b ; global_load_lds width=16 into LINEAR LDS tiles.
// z = 0:Q (M=4096), 1:K (M=4160), 2:V (M=4160). 128x128 tile, BK=64, 4 waves, 16x16x32 bf16.
__global__ __launch_bounds__(256) void gemm_qkv_kernel(
    const bf16* __restrict__ A, const bf16* __restrict__ Wt,
    const float* __restrict__ bQ, const float* __restrict__ bK, const float* __restrict__ bV,
    bf16* __restrict__ QKV) {
  const int z = blockIdx.z;
  const int M = (z == 0) ? SEQ : MALL;
  const int m0 = blockIdx.y * 128;
  if (m0 >= M) return;
  const int n0 = blockIdx.x * 128;
  const bf16* Wz = Wt + (size_t)z * DIMN * DIMN;
  const float* bias = (z == 0) ? bQ : ((z == 1) ? bK : bV);
  bf16* out = QKV + (size_t)z * MALL * DIMN;

  __shared__ bf16 As[128 * 64];   // linear: row*64 + col  (global_load_lds dest)
  __shared__ bf16 Bs[128 * 64];
  const int t = threadIdx.x;
  const int lane = t & 63, w = t >> 6;
  const int wr = w >> 1, wc = w & 1;
  const int r16 = lane & 15, g4 = lane >> 4;
  f32x4 acc[4][4] = {};

  // Per-issue geometry: segment = (i*4 + w)*64 + lane covers 8 rows x 8 bf16 chunks.
  // LDS base (wave-uniform) = segment_start * 8 bf16; HW adds lane*16B.
  for (int kt = 0; kt < 16; ++kt) {
    __syncthreads();  // previous compute done reading LDS
#pragma unroll
    for (int i = 0; i < 4; ++i) {
      int segBase = (i * 4 + w) * 64;
      int seg = segBase + lane;
      int row = seg >> 3, cc = seg & 7;
      int gm = m0 + row; gm = (gm < M) ? gm : (M - 1);
      __builtin_amdgcn_global_load_lds(
          (gvoid_t*)(A + (size_t)gm * DIMN + kt * 64 + cc * 8),
          (lvoid_t*)(As + (size_t)segBase * 8), 16, 0, 0);
      __builtin_amdgcn_global_load_lds(
          (gvoid_t*)(Wz + (size_t)(n0 + row) * DIMN + kt * 64 + cc * 8),
          (lvoid_t*)(Bs + (size_t)segBase * 8), 16, 0, 0);
    }
    __syncthreads();  // drains vmcnt -> tiles resident
#pragma unroll
    for (int kk = 0; kk < 2; ++kk) {
      bf16x8 af[4], bfr[4];
#pragma unroll
      for (int mi = 0; mi < 4; ++mi)
        af[mi] = *(const bf16x8*)&As[(wr * 64 + mi * 16 + r16) * 64 + kk * 32 + g4 * 8];
#pragma unroll
      for (int nj = 0; nj < 4; ++nj)
        bfr[nj] = *(const bf16x8*)&Bs[(wc * 64 + nj * 16 + r16) * 64 + kk * 32 + g4 * 8];
#pragma unroll
      for (int mi = 0; mi < 4; ++mi)
#pragma unroll
        for (int nj = 0; nj < 4; ++nj)
          acc[mi][nj] = __builtin_amdgcn_mfma_f32_16x16x32_bf16(af[mi], bfr[nj], acc[mi][nj], 0, 0, 0);
    }
  }
#pragma unroll
  for (int nj = 0; nj < 4; ++nj) {
    int n = n0 + wc * 64 + nj * 16 + r16;
    float bv = bias[n];
#pragma unroll
    for (int mi = 0; mi < 4; ++mi) {
      int mbase = m0 + wr * 64 + mi * 16 + g4 * 4;
#pragma unroll
      for (int r = 0; r < 4; ++r) {
        int m = mbase + r;
        if (m < M) out[(size_t)m * DIMN + n] = (bf16)(acc[mi][nj][r] + bv);
      }
    }
  }
}

// ---------------------------------------------------------------- key slot -> global row map (band paths)
__device__ __forceinline__ int key_row_map(int qb, int tslot) {
  if (qb <= 1) return tslot;                                    // rows 0..255
  if (qb == 63) return (tslot < 64) ? tslot : (3840 + tslot);   // block0 then blocks 61..63
  return (tslot < 64) ? tslot : ((qb - 1) * 64 + (tslot - 64)); // block0 + 3-block window
}

// ---------------------------------------------------------------- fused attention
// grid (64 qblocks, 8 heads), 256 threads (4 waves x 16 queries each).
__global__ __launch_bounds__(256) void attn_kernel(
    const bf16* __restrict__ Q, const bf16* __restrict__ K, const bf16* __restrict__ V,
    const float* __restrict__ mask, float* __restrict__ out) {
  const int qb = blockIdx.x, h = blockIdx.y;
  const int t = threadIdx.x;
  const int lane = t & 63, w = t >> 6;
  const int c16 = lane & 15, g4 = lane >> 4;
  const float sl = exp2f(-(float)(h + 1));
  const float rsq = 0.088388347648318447f;  // 1/sqrt(128)

  __shared__ bf16 KV[9216];      // union: K tile [64][136] (8704) | V^T tile [128][72] (9216)
  __shared__ bf16 P[64][264];    // probabilities, bf16, padded

  // --- Q fragments straight from global (each wave's own 16 query rows)
  bf16x8 qf[4];
  {
    int srow = qb * 64 + w * 16 + c16;
    const bf16* qp = Q + (size_t)srow * DIMN + h * HD + g4 * 8;
#pragma unroll
    for (int ks = 0; ks < 4; ++ks) qf[ks] = *(const bf16x8*)(qp + ks * 32);
  }

  int iq[4]; float mi[4];
#pragma unroll
  for (int r = 0; r < 4; ++r) { iq[r] = qb * 64 + w * 16 + g4 * 4 + r; mi[r] = mask[iq[r]]; }

  // --- band scores: 4 chunks x 64 keys
  f32x4 sc[16] = {};
#pragma unroll
  for (int c = 0; c < 4; ++c) {
    __syncthreads();
#pragma unroll
    for (int i = 0; i < 4; ++i) {
      int idx = i * 256 + t;
      int kr = idx >> 4, dc = idx & 15;
      int gr = key_row_map(qb, c * 64 + kr);
      *(bf16x8*)&KV[kr * 136 + dc * 8] = *(const bf16x8*)&K[(size_t)gr * DIMN + h * HD + dc * 8];
    }
    __syncthreads();
#pragma unroll
    for (int ks = 0; ks < 4; ++ks)
#pragma unroll
      for (int kj = 0; kj < 4; ++kj) {
        bf16x8 bfr = *(const bf16x8*)&KV[(kj * 16 + c16) * 136 + ks * 32 + g4 * 8];
        sc[c * 4 + kj] = __builtin_amdgcn_mfma_f32_16x16x32_bf16(qf[ks], bfr, sc[c * 4 + kj], 0, 0, 0);
      }
  }

  // --- bias (distance + mask penalties) — replicates reference quirks exactly
#pragma unroll
  for (int f = 0; f < 16; ++f) {
    int tslot = f * 16 + c16;
    int jrow = key_row_map(qb, tslot);
    float mj = mask[jrow];
    int jpos = (qb == 63) ? (3840 + tslot) : jrow;   // last block: virtual key positions
    int ishift = (qb >= 2 && qb <= 62) ? 128 : 0;    // middle band: row counter from 0 quirk
#pragma unroll
    for (int r = 0; r < 4; ++r) {
      float raw = sc[f][r];
      float dist = sl * fabsf((float)(iq[r] - ishift - jpos));
      float s;
      if (qb <= 1)       s = raw * rsq - dist + (1.f - mi[r]) * PENV;
      else if (qb == 63) s = raw * rsq - dist;
      else {
        float pen = (tslot < 64) ? (1.f - mi[r]) * PENV : (1.f - mi[r] * mj) * PENV;
        s = (raw + pen) * rsq - dist;
      }
      sc[f][r] = s;
    }
  }

  // --- in-wave softmax over 256 keys (per query row), normalize, P -> LDS
  {
#pragma unroll
    for (int r = 0; r < 4; ++r) {
      float m = -1e30f;
#pragma unroll
      for (int f = 0; f < 16; ++f) m = fmaxf(m, sc[f][r]);
#pragma unroll
      for (int d = 1; d < 16; d <<= 1) m = fmaxf(m, __shfl_xor(m, d));
      float s = 0.f;
#pragma unroll
      for (int f = 0; f < 16; ++f) { float e = __expf(sc[f][r] - m); sc[f][r] = e; s += e; }
#pragma unroll
      for (int d = 1; d < 16; d <<= 1) s += __shfl_xor(s, d);
      float inv = 1.0f / s;
#pragma unroll
      for (int f = 0; f < 16; ++f)
        P[w * 16 + g4 * 4 + r][f * 16 + c16] = (bf16)(sc[f][r] * inv);
    }
  }

  // --- band PV: 4 chunks, V staged transposed
  f32x4 ctx[8] = {};
#pragma unroll
  for (int c = 0; c < 4; ++c) {
    __syncthreads();  // all waves done with KV (scores) / previous chunk
#pragma unroll
    for (int i = 0; i < 4; ++i) {
      int idx = i * 256 + t;
      int vr = idx >> 4, dc = idx & 15;
      int gr = key_row_map(qb, c * 64 + vr);
      bf16x8 vv = *(const bf16x8*)&V[(size_t)gr * DIMN + h * HD + dc * 8];
#pragma unroll
      for (int j = 0; j < 8; ++j) KV[(dc * 8 + j) * 72 + vr] = vv[j];
    }
    __syncthreads();
#pragma unroll
    for (int ks = 0; ks < 2; ++ks) {
      bf16x8 pa = *(const bf16x8*)&P[w * 16 + c16][c * 64 + ks * 32 + g4 * 8];
#pragma unroll
      for (int df = 0; df < 8; ++df) {
        bf16x8 bv = *(const bf16x8*)&KV[(df * 16 + c16) * 72 + ks * 32 + g4 * 8];
        ctx[df] = __builtin_amdgcn_mfma_f32_16x16x32_bf16(pa, bv, ctx[df], 0, 0, 0);
      }
    }
  }

  // --- packed path (64 Cp keys, separate softmax; constants cancel so score = raw*rsq)
  __syncthreads();
#pragma unroll
  for (int i = 0; i < 4; ++i) {
    int idx = i * 256 + t;
    int kr = idx >> 4, dc = idx & 15;
    *(bf16x8*)&KV[kr * 136 + dc * 8] = *(const bf16x8*)&K[(size_t)(SEQ + kr) * DIMN + h * HD + dc * 8];
  }
  __syncthreads();
  f32x4 sp[4] = {};
#pragma unroll
  for (int ks = 0; ks < 4; ++ks)
#pragma unroll
    for (int kj = 0; kj < 4; ++kj) {
      bf16x8 bfr = *(const bf16x8*)&KV[(kj * 16 + c16) * 136 + ks * 32 + g4 * 8];
      sp[kj] = __builtin_amdgcn_mfma_f32_16x16x32_bf16(qf[ks], bfr, sp[kj], 0, 0, 0);
    }
#pragma unroll
  for (int r = 0; r < 4; ++r) {
    float m = -1e30f;
#pragma unroll
    for (int kj = 0; kj < 4; ++kj) m = fmaxf(m, sp[kj][r] * rsq);
#pragma unroll
    for (int d = 1; d < 16; d <<= 1) m = fmaxf(m, __shfl_xor(m, d));
    float s = 0.f;
    float e[4];
#pragma unroll
    for (int kj = 0; kj < 4; ++kj) { e[kj] = __expf(sp[kj][r] * rsq - m); s += e[kj]; }
#pragma unroll
    for (int d = 1; d < 16; d <<= 1) s += __shfl_xor(s, d);
    float inv = mi[r] / s;  // packed context is pre-scaled by mask_v
#pragma unroll
    for (int kj = 0; kj < 4; ++kj)
      P[w * 16 + g4 * 4 + r][kj * 16 + c16] = (bf16)(e[kj] * inv);
  }
  __syncthreads();  // all waves done reading KV (packed scores) before V^T restage
#pragma unroll
  for (int i = 0; i < 4; ++i) {
    int idx = i * 256 + t;
    int vr = idx >> 4, dc = idx & 15;
    bf16x8 vv = *(const bf16x8*)&V[(size_t)(SEQ + vr) * DIMN + h * HD + dc * 8];
#pragma unroll
    for (int j = 0; j < 8; ++j) KV[(dc * 8 + j) * 72 + vr] = vv[j];
  }
  __syncthreads();
#pragma unroll
  for (int ks = 0; ks < 2; ++ks) {
    bf16x8 pa = *(const bf16x8*)&P[w * 16 + c16][ks * 32 + g4 * 8];
#pragma unroll
    for (int df = 0; df < 8; ++df) {
      bf16x8 bv = *(const bf16x8*)&KV[(df * 16 + c16) * 72 + ks * 32 + g4 * 8];
      ctx[df] = __builtin_amdgcn_mfma_f32_16x16x32_bf16(pa, bv, ctx[df], 0, 0, 0);
    }
  }

  // --- output: raw [H,S,hd] flatten; final mask uses the reshaped row quirk mask[h*512 + s/8]
#pragma unroll
  for (int df = 0; df < 8; ++df) {
    int d = df * 16 + c16;
#pragma unroll
    for (int r = 0; r < 4; ++r) {
      int s = iq[r];
      float fm = mask[h * 512 + (s >> 3)];
      out[(size_t)h * (SEQ * HD) + (size_t)s * HD + d] = ctx[df][r] * fm;
    }
  }
}

// ---------------------------------------------------------------- launch
extern "C" void kernel_launch(void* const* d_in, const int* in_sizes, int n_in,
                              void* d_out, int out_size, void* d_ws, size_t ws_size,
                              hipStream_t stream) {
  const float* X    = (const float*)d_in[0];
  const float* Cp   = (const float*)d_in[1];
  const float* mask = (const float*)d_in[2];
  const float* WQ   = (const float*)d_in[3];
  const float* bQ   = (const float*)d_in[4];
  const float* WK   = (const float*)d_in[5];
  const float* bK   = (const float*)d_in[6];
  const float* WV   = (const float*)d_in[7];
  const float* bV   = (const float*)d_in[8];
  float* out = (float*)d_out;

  bf16* Abf = (bf16*)d_ws;                              // [4160][1024]
  bf16* Wt  = Abf + (size_t)MALL * DIMN;                // 3 x [1024][1024] (transposed)
  bf16* QKV = Wt + (size_t)3 * DIMN * DIMN;             // 3 x [4160][1024]: q, k, v

  int nCvt = (MALL * DIMN / 4 + 255) / 256;
  cvt_cat_kernel<<<nCvt, 256, 0, stream>>>(X, Cp, Abf);
  cvt_trans_kernel<<<dim3(16, 16, 3), 256, 0, stream>>>(WQ, WK, WV, Wt);
  gemm_qkv_kernel<<<dim3(8, 33, 3), 256, 0, stream>>>(Abf, Wt, bQ, bK, bV, QKV);
  attn_kernel<<<dim3(64, 8), 256, 0, stream>>>(QKV, QKV + (size_t)MALL * DIMN,
                                               QKV + (size_t)2 * MALL * DIMN, mask, out);
}

// Round 3
// 110.248 us; speedup vs baseline: 1.1320x; 1.1320x over previous
//
#include <hip/hip_runtime.h>
#include <hip/hip_bf16.h>

typedef __bf16 bf16;
typedef __attribute__((ext_vector_type(4))) __bf16 bf16x4;
typedef __attribute__((ext_vector_type(8))) __bf16 bf16x8;
typedef __attribute__((ext_vector_type(4))) float f32x4;

#define SEQ   4096
#define DIMN  1024
#define NHEAD 8
#define HD    128
#define MALL  4160   /* 4096 X rows + 64 Cp rows */
#define PENV  -10000.0f

typedef const __attribute__((address_space(1))) void gvoid_t;
typedef __attribute__((address_space(3))) void lvoid_t;

// ---------------------------------------------------------------- cvt: fp32 -> bf16, X ++ Cp
__global__ __launch_bounds__(256) void cvt_cat_kernel(
    const float* __restrict__ X, const float* __restrict__ Cp, bf16* __restrict__ A) {
  int i = blockIdx.x * 256 + threadIdx.x;
  size_t base = (size_t)i * 4;
  if (base >= (size_t)MALL * DIMN) return;
  const float* src = (base < (size_t)SEQ * DIMN) ? (X + base) : (Cp + (base - (size_t)SEQ * DIMN));
  float4 v = *(const float4*)src;
  bf16x4 o;
  o[0] = (bf16)v.x; o[1] = (bf16)v.y; o[2] = (bf16)v.z; o[3] = (bf16)v.w;
  *(bf16x4*)&A[base] = o;
}

// ---------------------------------------------------------------- cvt+transpose W[k][n] -> Wt[n][k] bf16
__global__ __launch_bounds__(256) void cvt_trans_kernel(
    const float* __restrict__ W0, const float* __restrict__ W1, const float* __restrict__ W2,
    bf16* __restrict__ Wt) {
  const float* W = (blockIdx.z == 0) ? W0 : ((blockIdx.z == 1) ? W1 : W2);
  bf16* dst = Wt + (size_t)blockIdx.z * DIMN * DIMN;
  __shared__ bf16 tile[64][72];
  int k0 = blockIdx.y * 64, n0 = blockIdx.x * 64;
  int tx = threadIdx.x & 63, ty = threadIdx.x >> 6;
#pragma unroll
  for (int r = ty; r < 64; r += 4)
    tile[tx][r] = (bf16)W[(size_t)(k0 + r) * DIMN + n0 + tx];
  __syncthreads();
#pragma unroll
  for (int r = ty; r < 64; r += 4)
    dst[(size_t)(n0 + r) * DIMN + k0 + tx] = tile[r][tx];
}

// ---------------------------------------------------------------- fused QKV GEMM (m97 structure + T2 swizzle):
// out = A @ W^T(stored [n][k]) + b ; global_load_lds width=16 into LINEAR LDS tiles,
// XOR chunk swizzle applied on SOURCE (stage) and READ sides (rule #21 both-sides).
// z = 0:Q [m][n], 1:K [m][n], 2:V stored TRANSPOSED VT[n][m]. 128x128 tile, BK=64, 4 waves.
__global__ __launch_bounds__(256) void gemm_qkv_kernel(
    const bf16* __restrict__ A, const bf16* __restrict__ Wt,
    const float* __restrict__ bQ, const float* __restrict__ bK, const float* __restrict__ bV,
    bf16* __restrict__ QKV) {
  const int z = blockIdx.z;
  const int M = (z == 0) ? SEQ : MALL;
  const int m0 = blockIdx.y * 128;
  if (m0 >= M) return;
  const int n0 = blockIdx.x * 128;
  const bf16* Wz = Wt + (size_t)z * DIMN * DIMN;
  const float* bias = (z == 0) ? bQ : ((z == 1) ? bK : bV);
  bf16* out = QKV + (size_t)z * MALL * DIMN;

  __shared__ bf16 As[128 * 64];   // linear rows of 64; chunk c of row r holds logical chunk c^(r&7)
  __shared__ bf16 Bs[128 * 64];
  const int t = threadIdx.x;
  const int lane = t & 63, w = t >> 6;
  const int wr = w >> 1, wc = w & 1;
  const int r16 = lane & 15, g4 = lane >> 4;
  f32x4 acc[4][4] = {};

  for (int kt = 0; kt < 16; ++kt) {
    __syncthreads();  // previous compute done reading LDS
#pragma unroll
    for (int i = 0; i < 4; ++i) {
      int segBase = (i * 4 + w) * 64;
      int seg = segBase + lane;
      int row = seg >> 3;
      int cc = (seg & 7) ^ (row & 7);          // source-side swizzle
      int gm = m0 + row; gm = (gm < M) ? gm : (M - 1);
      __builtin_amdgcn_global_load_lds(
          (gvoid_t*)(A + (size_t)gm * DIMN + kt * 64 + cc * 8),
          (lvoid_t*)(As + (size_t)segBase * 8), 16, 0, 0);
      __builtin_amdgcn_global_load_lds(
          (gvoid_t*)(Wz + (size_t)(n0 + row) * DIMN + kt * 64 + cc * 8),
          (lvoid_t*)(Bs + (size_t)segBase * 8), 16, 0, 0);
    }
    __syncthreads();  // drains vmcnt -> tiles resident
#pragma unroll
    for (int kk = 0; kk < 2; ++kk) {
      bf16x8 af[4], bfr[4];
#pragma unroll
      for (int mi = 0; mi < 4; ++mi) {
        int rowA = wr * 64 + mi * 16 + r16;
        af[mi] = *(const bf16x8*)&As[rowA * 64 + (((kk * 4 + g4) ^ (rowA & 7)) * 8)];
      }
#pragma unroll
      for (int nj = 0; nj < 4; ++nj) {
        int rowB = wc * 64 + nj * 16 + r16;
        bfr[nj] = *(const bf16x8*)&Bs[rowB * 64 + (((kk * 4 + g4) ^ (rowB & 7)) * 8)];
      }
#pragma unroll
      for (int mi = 0; mi < 4; ++mi)
#pragma unroll
        for (int nj = 0; nj < 4; ++nj)
          acc[mi][nj] = __builtin_amdgcn_mfma_f32_16x16x32_bf16(af[mi], bfr[nj], acc[mi][nj], 0, 0, 0);
    }
  }
  if (z == 2) {
    // V epilogue: write TRANSPOSED  VT[n][m], n in [0,1024), m in [0,4160).
    // Each thread owns 4 consecutive m -> one 8B store.
#pragma unroll
    for (int nj = 0; nj < 4; ++nj) {
      int n = n0 + wc * 64 + nj * 16 + r16;
      float bv = bias[n];
#pragma unroll
      for (int mi = 0; mi < 4; ++mi) {
        int mbase = m0 + wr * 64 + mi * 16 + g4 * 4;
        if (mbase < M) {
          bf16x4 o;
#pragma unroll
          for (int r = 0; r < 4; ++r) o[r] = (bf16)(acc[mi][nj][r] + bv);
          *(bf16x4*)&out[(size_t)n * MALL + mbase] = o;
        }
      }
    }
  } else {
#pragma unroll
    for (int nj = 0; nj < 4; ++nj) {
      int n = n0 + wc * 64 + nj * 16 + r16;
      float bv = bias[n];
#pragma unroll
      for (int mi = 0; mi < 4; ++mi) {
        int mbase = m0 + wr * 64 + mi * 16 + g4 * 4;
#pragma unroll
        for (int r = 0; r < 4; ++r) {
          int m = mbase + r;
          if (m < M) out[(size_t)m * DIMN + n] = (bf16)(acc[mi][nj][r] + bv);
        }
      }
    }
  }
}

// ---------------------------------------------------------------- key slot -> global row map (band paths)
__device__ __forceinline__ int key_row_map(int qb, int tslot) {
  if (qb <= 1) return tslot;                                    // rows 0..255
  if (qb == 63) return (tslot < 64) ? tslot : (3840 + tslot);   // block0 then blocks 61..63
  return (tslot < 64) ? tslot : ((qb - 1) * 64 + (tslot - 64)); // block0 + 3-block window
}

// ---------------------------------------------------------------- fused attention
// grid (64 qblocks, 8 heads), 256 threads (4 waves x 16 queries each).
// K staged in LDS; V read directly from global VT[d][row] (L2-resident, 3x reuse).
__global__ __launch_bounds__(256) void attn_kernel(
    const bf16* __restrict__ Q, const bf16* __restrict__ K, const bf16* __restrict__ VT,
    const float* __restrict__ mask, float* __restrict__ out) {
  const int qb = blockIdx.x, h = blockIdx.y;
  const int t = threadIdx.x;
  const int lane = t & 63, w = t >> 6;
  const int c16 = lane & 15, g4 = lane >> 4;
  const float sl = exp2f(-(float)(h + 1));
  const float rsq = 0.088388347648318447f;  // 1/sqrt(128)

  __shared__ bf16 KV[64 * 136];  // K tile [64][136]
  __shared__ bf16 P[64][264];    // probabilities, bf16, padded

  // --- Q fragments straight from global (each wave's own 16 query rows)
  bf16x8 qf[4];
  {
    int srow = qb * 64 + w * 16 + c16;
    const bf16* qp = Q + (size_t)srow * DIMN + h * HD + g4 * 8;
#pragma unroll
    for (int ks = 0; ks < 4; ++ks) qf[ks] = *(const bf16x8*)(qp + ks * 32);
  }

  int iq[4]; float mi[4];
#pragma unroll
  for (int r = 0; r < 4; ++r) { iq[r] = qb * 64 + w * 16 + g4 * 4 + r; mi[r] = mask[iq[r]]; }

  // --- band scores: 4 chunks x 64 keys
  f32x4 sc[16] = {};
#pragma unroll
  for (int c = 0; c < 4; ++c) {
    __syncthreads();
#pragma unroll
    for (int i = 0; i < 4; ++i) {
      int idx = i * 256 + t;
      int kr = idx >> 4, dc = idx & 15;
      int gr = key_row_map(qb, c * 64 + kr);
      *(bf16x8*)&KV[kr * 136 + dc * 8] = *(const bf16x8*)&K[(size_t)gr * DIMN + h * HD + dc * 8];
    }
    __syncthreads();
#pragma unroll
    for (int ks = 0; ks < 4; ++ks)
#pragma unroll
      for (int kj = 0; kj < 4; ++kj) {
        bf16x8 bfr = *(const bf16x8*)&KV[(kj * 16 + c16) * 136 + ks * 32 + g4 * 8];
        sc[c * 4 + kj] = __builtin_amdgcn_mfma_f32_16x16x32_bf16(qf[ks], bfr, sc[c * 4 + kj], 0, 0, 0);
      }
  }

  // --- bias (distance + mask penalties) — replicates reference quirks exactly
#pragma unroll
  for (int f = 0; f < 16; ++f) {
    int tslot = f * 16 + c16;
    int jrow = key_row_map(qb, tslot);
    float mj = mask[jrow];
    int jpos = (qb == 63) ? (3840 + tslot) : jrow;   // last block: virtual key positions
    int ishift = (qb >= 2 && qb <= 62) ? 128 : 0;    // middle band: row counter from 0 quirk
#pragma unroll
    for (int r = 0; r < 4; ++r) {
      float raw = sc[f][r];
      float dist = sl * fabsf((float)(iq[r] - ishift - jpos));
      float s;
      if (qb <= 1)       s = raw * rsq - dist + (1.f - mi[r]) * PENV;
      else if (qb == 63) s = raw * rsq - dist;
      else {
        float pen = (tslot < 64) ? (1.f - mi[r]) * PENV : (1.f - mi[r] * mj) * PENV;
        s = (raw + pen) * rsq - dist;
      }
      sc[f][r] = s;
    }
  }

  // --- in-wave softmax over 256 keys (per query row), normalize, P -> LDS
#pragma unroll
  for (int r = 0; r < 4; ++r) {
    float m = -1e30f;
#pragma unroll
    for (int f = 0; f < 16; ++f) m = fmaxf(m, sc[f][r]);
#pragma unroll
    for (int d = 1; d < 16; d <<= 1) m = fmaxf(m, __shfl_xor(m, d));
    float s = 0.f;
#pragma unroll
    for (int f = 0; f < 16; ++f) { float e = __expf(sc[f][r] - m); sc[f][r] = e; s += e; }
#pragma unroll
    for (int d = 1; d < 16; d <<= 1) s += __shfl_xor(s, d);
    float inv = 1.0f / s;
#pragma unroll
    for (int f = 0; f < 16; ++f)
      P[w * 16 + g4 * 4 + r][f * 16 + c16] = (bf16)(sc[f][r] * inv);
  }

  // --- band PV: B-fragments straight from global VT (no LDS staging, no barriers)
  f32x4 ctx[8] = {};
  const bf16* vt_h = VT + (size_t)h * HD * MALL;
#pragma unroll
  for (int c = 0; c < 4; ++c) {
    int kst = key_row_map(qb, c * 64);  // chunk = 64 contiguous rows
#pragma unroll
    for (int ks = 0; ks < 2; ++ks) {
      bf16x8 pa = *(const bf16x8*)&P[w * 16 + c16][c * 64 + ks * 32 + g4 * 8];
#pragma unroll
      for (int df = 0; df < 8; ++df) {
        bf16x8 bv = *(const bf16x8*)&vt_h[(size_t)(df * 16 + c16) * MALL + kst + ks * 32 + g4 * 8];
        ctx[df] = __builtin_amdgcn_mfma_f32_16x16x32_bf16(pa, bv, ctx[df], 0, 0, 0);
      }
    }
  }

  // --- packed path (64 Cp keys, separate softmax; constants cancel so score = raw*rsq)
  __syncthreads();  // all waves done with KV (band scores) before restage
#pragma unroll
  for (int i = 0; i < 4; ++i) {
    int idx = i * 256 + t;
    int kr = idx >> 4, dc = idx & 15;
    *(bf16x8*)&KV[kr * 136 + dc * 8] = *(const bf16x8*)&K[(size_t)(SEQ + kr) * DIMN + h * HD + dc * 8];
  }
  __syncthreads();
  f32x4 sp[4] = {};
#pragma unroll
  for (int ks = 0; ks < 4; ++ks)
#pragma unroll
    for (int kj = 0; kj < 4; ++kj) {
      bf16x8 bfr = *(const bf16x8*)&KV[(kj * 16 + c16) * 136 + ks * 32 + g4 * 8];
      sp[kj] = __builtin_amdgcn_mfma_f32_16x16x32_bf16(qf[ks], bfr, sp[kj], 0, 0, 0);
    }
#pragma unroll
  for (int r = 0; r < 4; ++r) {
    float m = -1e30f;
#pragma unroll
    for (int kj = 0; kj < 4; ++kj) m = fmaxf(m, sp[kj][r] * rsq);
#pragma unroll
    for (int d = 1; d < 16; d <<= 1) m = fmaxf(m, __shfl_xor(m, d));
    float s = 0.f;
    float e[4];
#pragma unroll
    for (int kj = 0; kj < 4; ++kj) { e[kj] = __expf(sp[kj][r] * rsq - m); s += e[kj]; }
#pragma unroll
    for (int d = 1; d < 16; d <<= 1) s += __shfl_xor(s, d);
    float inv = mi[r] / s;  // packed context is pre-scaled by mask_v
#pragma unroll
    for (int kj = 0; kj < 4; ++kj)
      P[w * 16 + g4 * 4 + r][kj * 16 + c16] = (bf16)(e[kj] * inv);
  }
  // packed PV: VT rows at cols SEQ..SEQ+63
#pragma unroll
  for (int ks = 0; ks < 2; ++ks) {
    bf16x8 pa = *(const bf16x8*)&P[w * 16 + c16][ks * 32 + g4 * 8];
#pragma unroll
    for (int df = 0; df < 8; ++df) {
      bf16x8 bv = *(const bf16x8*)&vt_h[(size_t)(df * 16 + c16) * MALL + SEQ + ks * 32 + g4 * 8];
      ctx[df] = __builtin_amdgcn_mfma_f32_16x16x32_bf16(pa, bv, ctx[df], 0, 0, 0);
    }
  }

  // --- output: raw [H,S,hd] flatten; final mask uses the reshaped row quirk mask[h*512 + s/8]
#pragma unroll
  for (int df = 0; df < 8; ++df) {
    int d = df * 16 + c16;
#pragma unroll
    for (int r = 0; r < 4; ++r) {
      int s = iq[r];
      float fm = mask[h * 512 + (s >> 3)];
      out[(size_t)h * (SEQ * HD) + (size_t)s * HD + d] = ctx[df][r] * fm;
    }
  }
}

// ---------------------------------------------------------------- launch
extern "C" void kernel_launch(void* const* d_in, const int* in_sizes, int n_in,
                              void* d_out, int out_size, void* d_ws, size_t ws_size,
                              hipStream_t stream) {
  const float* X    = (const float*)d_in[0];
  const float* Cp   = (const float*)d_in[1];
  const float* mask = (const float*)d_in[2];
  const float* WQ   = (const float*)d_in[3];
  const float* bQ   = (const float*)d_in[4];
  const float* WK   = (const float*)d_in[5];
  const float* bK   = (const float*)d_in[6];
  const float* WV   = (const float*)d_in[7];
  const float* bV   = (const float*)d_in[8];
  float* out = (float*)d_out;

  bf16* Abf = (bf16*)d_ws;                              // [4160][1024]
  bf16* Wt  = Abf + (size_t)MALL * DIMN;                // 3 x [1024][1024] (transposed)
  bf16* QKV = Wt + (size_t)3 * DIMN * DIMN;             // q[4160][1024], k[4160][1024], VT[1024][4160]

  int nCvt = (MALL * DIMN / 4 + 255) / 256;
  cvt_cat_kernel<<<nCvt, 256, 0, stream>>>(X, Cp, Abf);
  cvt_trans_kernel<<<dim3(16, 16, 3), 256, 0, stream>>>(WQ, WK, WV, Wt);
  gemm_qkv_kernel<<<dim3(8, 33, 3), 256, 0, stream>>>(Abf, Wt, bQ, bK, bV, QKV);
  attn_kernel<<<dim3(64, 8), 256, 0, stream>>>(QKV, QKV + (size_t)MALL * DIMN,
                                               QKV + (size_t)2 * MALL * DIMN, mask, out);
}

// Round 4
// 104.258 us; speedup vs baseline: 1.1971x; 1.0575x over previous
//
#include <hip/hip_runtime.h>
#include <hip/hip_bf16.h>

typedef __bf16 bf16;
typedef __attribute__((ext_vector_type(4))) __bf16 bf16x4;
typedef __attribute__((ext_vector_type(8))) __bf16 bf16x8;
typedef __attribute__((ext_vector_type(4))) float f32x4;

#define SEQ   4096
#define DIMN  1024
#define NHEAD 8
#define HD    128
#define MALL  4160   /* 4096 X rows + 64 Cp rows */
#define PENV  -10000.0f
#define BK    64
#define NT    (DIMN / BK)   /* 16 K-tiles */

typedef const __attribute__((address_space(1))) void gvoid_t;
typedef __attribute__((address_space(3))) void lvoid_t;

// Raw barrier with compiler memory fences on both sides: no implicit vmcnt(0) drain
// (unlike __syncthreads), but loads cannot be hoisted/sunk across it.
#define RAW_BARRIER() do {                      \
    asm volatile("" ::: "memory");              \
    __builtin_amdgcn_s_barrier();               \
    asm volatile("" ::: "memory");              \
  } while (0)

// ---------------------------------------------------------------- cvt: fp32 -> bf16, X ++ Cp
__global__ __launch_bounds__(256) void cvt_cat_kernel(
    const float* __restrict__ X, const float* __restrict__ Cp, bf16* __restrict__ A) {
  int i = blockIdx.x * 256 + threadIdx.x;
  size_t base = (size_t)i * 4;
  if (base >= (size_t)MALL * DIMN) return;
  const float* src = (base < (size_t)SEQ * DIMN) ? (X + base) : (Cp + (base - (size_t)SEQ * DIMN));
  float4 v = *(const float4*)src;
  bf16x4 o;
  o[0] = (bf16)v.x; o[1] = (bf16)v.y; o[2] = (bf16)v.z; o[3] = (bf16)v.w;
  *(bf16x4*)&A[base] = o;
}

// ---------------------------------------------------------------- cvt+transpose W[k][n] -> Wt[n][k] bf16
__global__ __launch_bounds__(256) void cvt_trans_kernel(
    const float* __restrict__ W0, const float* __restrict__ W1, const float* __restrict__ W2,
    bf16* __restrict__ Wt) {
  const float* W = (blockIdx.z == 0) ? W0 : ((blockIdx.z == 1) ? W1 : W2);
  bf16* dst = Wt + (size_t)blockIdx.z * DIMN * DIMN;
  __shared__ bf16 tile[64][72];
  int k0 = blockIdx.y * 64, n0 = blockIdx.x * 64;
  int tx = threadIdx.x & 63, ty = threadIdx.x >> 6;
#pragma unroll
  for (int r = ty; r < 64; r += 4)
    tile[tx][r] = (bf16)W[(size_t)(k0 + r) * DIMN + n0 + tx];
  __syncthreads();
#pragma unroll
  for (int r = ty; r < 64; r += 4)
    dst[(size_t)(n0 + r) * DIMN + k0 + tx] = tile[r][tx];
}

// ---------------------------------------------------------------- fused QKV GEMM, 256^2 tile,
// 8 waves (2M x 4N), BK=64, double-buffered LDS, counted vmcnt + raw barriers (T3+T4+T5).
// Chunk-XOR swizzle on SOURCE (stage) and READ sides; linear global_load_lds dest (rule #21).
// z = 0:Q [m][n], 1:K [m][n], 2:V stored TRANSPOSED VT[n][m].
__global__ __launch_bounds__(512) void gemm_qkv_kernel(
    const bf16* __restrict__ A, const bf16* __restrict__ Wt,
    const float* __restrict__ bQ, const float* __restrict__ bK, const float* __restrict__ bV,
    bf16* __restrict__ QKV) {
  const int z = blockIdx.z;
  const int M = (z == 0) ? SEQ : MALL;
  const int m0 = blockIdx.y * 256;
  if (m0 >= M) return;
  const int n0 = blockIdx.x * 256;
  const bf16* Wz = Wt + (size_t)z * DIMN * DIMN;
  const float* bias = (z == 0) ? bQ : ((z == 1) ? bK : bV);
  bf16* out = QKV + (size_t)z * MALL * DIMN;

  __shared__ bf16 Abuf[2][256 * 64];   // 32 KiB each; linear rows of 64, chunk-swizzled contents
  __shared__ bf16 Bbuf[2][256 * 64];

  const int t = threadIdx.x;
  const int lane = t & 63, w = t >> 6;
  const int wm = w >> 2, wn = w & 3;          // 2 x 4 wave grid
  const int r16 = lane & 15, g4 = lane >> 4;

  f32x4 acc[8][4] = {};

  // Stage one full K-tile (A 256x64 + B 256x64) into buffer b: 8 global_load_lds / thread.
  auto stage_tile = [&](int b, int u) {
#pragma unroll
    for (int h = 0; h < 2; ++h)
#pragma unroll
      for (int i = 0; i < 2; ++i) {
        int segBase = (i * 8 + w) * 64;
        int seg = segBase + lane;
        int row = seg >> 3;
        int cc = (seg & 7) ^ (row & 7);       // source-side swizzle
        int gm = m0 + h * 128 + row; gm = (gm < M) ? gm : (M - 1);
        __builtin_amdgcn_global_load_lds(
            (gvoid_t*)(A + (size_t)gm * DIMN + u * BK + cc * 8),
            (lvoid_t*)(&Abuf[b][h * 8192 + segBase * 8]), 16, 0, 0);
      }
#pragma unroll
    for (int h = 0; h < 2; ++h)
#pragma unroll
      for (int i = 0; i < 2; ++i) {
        int segBase = (i * 8 + w) * 64;
        int seg = segBase + lane;
        int row = seg >> 3;
        int cc = (seg & 7) ^ (row & 7);
        int gn = n0 + h * 128 + row;          // always < 1024
        __builtin_amdgcn_global_load_lds(
            (gvoid_t*)(Wz + (size_t)gn * DIMN + u * BK + cc * 8),
            (lvoid_t*)(&Bbuf[b][h * 8192 + segBase * 8]), 16, 0, 0);
      }
  };

  stage_tile(0, 0);

  for (int u = 0; u < NT; ++u) {
    const int q = u & 1;
    if (u + 1 < NT) {
      stage_tile(q ^ 1, u + 1);                         // 8 loads stay in flight across MFMAs
      asm volatile("s_waitcnt vmcnt(8)" ::: "memory");  // drain tile u's stages only
    } else {
      asm volatile("s_waitcnt vmcnt(0)" ::: "memory");
    }
    RAW_BARRIER();        // all waves' tile-u stages landed; no vmcnt(0) drain of tile u+1
    __builtin_amdgcn_sched_barrier(0);
#pragma unroll
    for (int kk = 0; kk < 2; ++kk) {
      bf16x8 bfr[4], af[8];
#pragma unroll
      for (int nf = 0; nf < 4; ++nf) {
        int rb = wn * 64 + nf * 16 + r16;
        bfr[nf] = *(const bf16x8*)&Bbuf[q][rb * 64 + (((kk * 4 + g4) ^ (rb & 7)) * 8)];
      }
#pragma unroll
      for (int mf = 0; mf < 8; ++mf) {
        int ra = wm * 128 + mf * 16 + r16;
        af[mf] = *(const bf16x8*)&Abuf[q][ra * 64 + (((kk * 4 + g4) ^ (ra & 7)) * 8)];
      }
      __builtin_amdgcn_s_setprio(1);
#pragma unroll
      for (int mf = 0; mf < 8; ++mf)
#pragma unroll
        for (int nf = 0; nf < 4; ++nf)
          acc[mf][nf] = __builtin_amdgcn_mfma_f32_16x16x32_bf16(af[mf], bfr[nf], acc[mf][nf], 0, 0, 0);
      __builtin_amdgcn_s_setprio(0);
    }
    RAW_BARRIER();        // all waves done reading buf q before next iter restages it
  }

  // ---- epilogue
  if (z == 2) {
    // V: write TRANSPOSED VT[n][m]; each thread owns 4 consecutive m -> one 8B store.
#pragma unroll
    for (int nf = 0; nf < 4; ++nf) {
      int n = n0 + wn * 64 + nf * 16 + r16;
      float bv = bias[n];
#pragma unroll
      for (int mf = 0; mf < 8; ++mf) {
        int mbase = m0 + wm * 128 + mf * 16 + g4 * 4;
        if (mbase < M) {
          bf16x4 o;
#pragma unroll
          for (int r = 0; r < 4; ++r) o[r] = (bf16)(acc[mf][nf][r] + bv);
          *(bf16x4*)&out[(size_t)n * MALL + mbase] = o;
        }
      }
    }
  } else {
#pragma unroll
    for (int nf = 0; nf < 4; ++nf) {
      int n = n0 + wn * 64 + nf * 16 + r16;
      float bv = bias[n];
#pragma unroll
      for (int mf = 0; mf < 8; ++mf) {
        int mbase = m0 + wm * 128 + mf * 16 + g4 * 4;
#pragma unroll
        for (int r = 0; r < 4; ++r) {
          int m = mbase + r;
          if (m < M) out[(size_t)m * DIMN + n] = (bf16)(acc[mf][nf][r] + bv);
        }
      }
    }
  }
}

// ---------------------------------------------------------------- key slot -> global row map (band paths)
__device__ __forceinline__ int key_row_map(int qb, int tslot) {
  if (qb <= 1) return tslot;                                    // rows 0..255
  if (qb == 63) return (tslot < 64) ? tslot : (3840 + tslot);   // block0 then blocks 61..63
  return (tslot < 64) ? tslot : ((qb - 1) * 64 + (tslot - 64)); // block0 + 3-block window
}

// ---------------------------------------------------------------- fused attention
// grid (64 qblocks, 8 heads), 256 threads (4 waves x 16 queries each).
// K staged in LDS; V read directly from global VT[d][row] (L2-resident, 3x reuse).
__global__ __launch_bounds__(256) void attn_kernel(
    const bf16* __restrict__ Q, const bf16* __restrict__ K, const bf16* __restrict__ VT,
    const float* __restrict__ mask, float* __restrict__ out) {
  const int qb = blockIdx.x, h = blockIdx.y;
  const int t = threadIdx.x;
  const int lane = t & 63, w = t >> 6;
  const int c16 = lane & 15, g4 = lane >> 4;
  const float sl = exp2f(-(float)(h + 1));
  const float rsq = 0.088388347648318447f;  // 1/sqrt(128)

  __shared__ bf16 KV[64 * 136];  // K tile [64][136]
  __shared__ bf16 P[64][264];    // probabilities, bf16, padded

  // --- Q fragments straight from global (each wave's own 16 query rows)
  bf16x8 qf[4];
  {
    int srow = qb * 64 + w * 16 + c16;
    const bf16* qp = Q + (size_t)srow * DIMN + h * HD + g4 * 8;
#pragma unroll
    for (int ks = 0; ks < 4; ++ks) qf[ks] = *(const bf16x8*)(qp + ks * 32);
  }

  int iq[4]; float mi[4];
#pragma unroll
  for (int r = 0; r < 4; ++r) { iq[r] = qb * 64 + w * 16 + g4 * 4 + r; mi[r] = mask[iq[r]]; }

  // --- band scores: 4 chunks x 64 keys
  f32x4 sc[16] = {};
#pragma unroll
  for (int c = 0; c < 4; ++c) {
    __syncthreads();
#pragma unroll
    for (int i = 0; i < 4; ++i) {
      int idx = i * 256 + t;
      int kr = idx >> 4, dc = idx & 15;
      int gr = key_row_map(qb, c * 64 + kr);
      *(bf16x8*)&KV[kr * 136 + dc * 8] = *(const bf16x8*)&K[(size_t)gr * DIMN + h * HD + dc * 8];
    }
    __syncthreads();
#pragma unroll
    for (int ks = 0; ks < 4; ++ks)
#pragma unroll
      for (int kj = 0; kj < 4; ++kj) {
        bf16x8 bfr = *(const bf16x8*)&KV[(kj * 16 + c16) * 136 + ks * 32 + g4 * 8];
        sc[c * 4 + kj] = __builtin_amdgcn_mfma_f32_16x16x32_bf16(qf[ks], bfr, sc[c * 4 + kj], 0, 0, 0);
      }
  }

  // --- bias (distance + mask penalties) — replicates reference quirks exactly
#pragma unroll
  for (int f = 0; f < 16; ++f) {
    int tslot = f * 16 + c16;
    int jrow = key_row_map(qb, tslot);
    float mj = mask[jrow];
    int jpos = (qb == 63) ? (3840 + tslot) : jrow;   // last block: virtual key positions
    int ishift = (qb >= 2 && qb <= 62) ? 128 : 0;    // middle band: row counter from 0 quirk
#pragma unroll
    for (int r = 0; r < 4; ++r) {
      float raw = sc[f][r];
      float dist = sl * fabsf((float)(iq[r] - ishift - jpos));
      float s;
      if (qb <= 1)       s = raw * rsq - dist + (1.f - mi[r]) * PENV;
      else if (qb == 63) s = raw * rsq - dist;
      else {
        float pen = (tslot < 64) ? (1.f - mi[r]) * PENV : (1.f - mi[r] * mj) * PENV;
        s = (raw + pen) * rsq - dist;
      }
      sc[f][r] = s;
    }
  }

  // --- in-wave softmax over 256 keys (per query row), normalize, P -> LDS
#pragma unroll
  for (int r = 0; r < 4; ++r) {
    float m = -1e30f;
#pragma unroll
    for (int f = 0; f < 16; ++f) m = fmaxf(m, sc[f][r]);
#pragma unroll
    for (int d = 1; d < 16; d <<= 1) m = fmaxf(m, __shfl_xor(m, d));
    float s = 0.f;
#pragma unroll
    for (int f = 0; f < 16; ++f) { float e = __expf(sc[f][r] - m); sc[f][r] = e; s += e; }
#pragma unroll
    for (int d = 1; d < 16; d <<= 1) s += __shfl_xor(s, d);
    float inv = 1.0f / s;
#pragma unroll
    for (int f = 0; f < 16; ++f)
      P[w * 16 + g4 * 4 + r][f * 16 + c16] = (bf16)(sc[f][r] * inv);
  }

  // --- band PV: B-fragments straight from global VT (no LDS staging, no barriers)
  f32x4 ctx[8] = {};
  const bf16* vt_h = VT + (size_t)h * HD * MALL;
#pragma unroll
  for (int c = 0; c < 4; ++c) {
    int kst = key_row_map(qb, c * 64);  // chunk = 64 contiguous rows
#pragma unroll
    for (int ks = 0; ks < 2; ++ks) {
      bf16x8 pa = *(const bf16x8*)&P[w * 16 + c16][c * 64 + ks * 32 + g4 * 8];
#pragma unroll
      for (int df = 0; df < 8; ++df) {
        bf16x8 bv = *(const bf16x8*)&vt_h[(size_t)(df * 16 + c16) * MALL + kst + ks * 32 + g4 * 8];
        ctx[df] = __builtin_amdgcn_mfma_f32_16x16x32_bf16(pa, bv, ctx[df], 0, 0, 0);
      }
    }
  }

  // --- packed path (64 Cp keys, separate softmax; constants cancel so score = raw*rsq)
  __syncthreads();  // all waves done with KV (band scores) before restage
#pragma unroll
  for (int i = 0; i < 4; ++i) {
    int idx = i * 256 + t;
    int kr = idx >> 4, dc = idx & 15;
    *(bf16x8*)&KV[kr * 136 + dc * 8] = *(const bf16x8*)&K[(size_t)(SEQ + kr) * DIMN + h * HD + dc * 8];
  }
  __syncthreads();
  f32x4 sp[4] = {};
#pragma unroll
  for (int ks = 0; ks < 4; ++ks)
#pragma unroll
    for (int kj = 0; kj < 4; ++kj) {
      bf16x8 bfr = *(const bf16x8*)&KV[(kj * 16 + c16) * 136 + ks * 32 + g4 * 8];
      sp[kj] = __builtin_amdgcn_mfma_f32_16x16x32_bf16(qf[ks], bfr, sp[kj], 0, 0, 0);
    }
#pragma unroll
  for (int r = 0; r < 4; ++r) {
    float m = -1e30f;
#pragma unroll
    for (int kj = 0; kj < 4; ++kj) m = fmaxf(m, sp[kj][r] * rsq);
#pragma unroll
    for (int d = 1; d < 16; d <<= 1) m = fmaxf(m, __shfl_xor(m, d));
    float s = 0.f;
    float e[4];
#pragma unroll
    for (int kj = 0; kj < 4; ++kj) { e[kj] = __expf(sp[kj][r] * rsq - m); s += e[kj]; }
#pragma unroll
    for (int d = 1; d < 16; d <<= 1) s += __shfl_xor(s, d);
    float inv = mi[r] / s;  // packed context is pre-scaled by mask_v
#pragma unroll
    for (int kj = 0; kj < 4; ++kj)
      P[w * 16 + g4 * 4 + r][kj * 16 + c16] = (bf16)(e[kj] * inv);
  }
  // packed PV: VT rows at cols SEQ..SEQ+63
#pragma unroll
  for (int ks = 0; ks < 2; ++ks) {
    bf16x8 pa = *(const bf16x8*)&P[w * 16 + c16][ks * 32 + g4 * 8];
#pragma unroll
    for (int df = 0; df < 8; ++df) {
      bf16x8 bv = *(const bf16x8*)&vt_h[(size_t)(df * 16 + c16) * MALL + SEQ + ks * 32 + g4 * 8];
      ctx[df] = __builtin_amdgcn_mfma_f32_16x16x32_bf16(pa, bv, ctx[df], 0, 0, 0);
    }
  }

  // --- output: raw [H,S,hd] flatten; final mask uses the reshaped row quirk mask[h*512 + s/8]
#pragma unroll
  for (int df = 0; df < 8; ++df) {
    int d = df * 16 + c16;
#pragma unroll
    for (int r = 0; r < 4; ++r) {
      int s = iq[r];
      float fm = mask[h * 512 + (s >> 3)];
      out[(size_t)h * (SEQ * HD) + (size_t)s * HD + d] = ctx[df][r] * fm;
    }
  }
}

// ---------------------------------------------------------------- launch
extern "C" void kernel_launch(void* const* d_in, const int* in_sizes, int n_in,
                              void* d_out, int out_size, void* d_ws, size_t ws_size,
                              hipStream_t stream) {
  const float* X    = (const float*)d_in[0];
  const float* Cp   = (const float*)d_in[1];
  const float* mask = (const float*)d_in[2];
  const float* WQ   = (const float*)d_in[3];
  const float* bQ   = (const float*)d_in[4];
  const float* WK   = (const float*)d_in[5];
  const float* bK   = (const float*)d_in[6];
  const float* WV   = (const float*)d_in[7];
  const float* bV   = (const float*)d_in[8];
  float* out = (float*)d_out;

  bf16* Abf = (bf16*)d_ws;                              // [4160][1024]
  bf16* Wt  = Abf + (size_t)MALL * DIMN;                // 3 x [1024][1024] (transposed)
  bf16* QKV = Wt + (size_t)3 * DIMN * DIMN;             // q[4160][1024], k[4160][1024], VT[1024][4160]

  int nCvt = (MALL * DIMN / 4 + 255) / 256;
  cvt_cat_kernel<<<nCvt, 256, 0, stream>>>(X, Cp, Abf);
  cvt_trans_kernel<<<dim3(16, 16, 3), 256, 0, stream>>>(WQ, WK, WV, Wt);
  gemm_qkv_kernel<<<dim3(4, 17, 3), 512, 0, stream>>>(Abf, Wt, bQ, bK, bV, QKV);
  attn_kernel<<<dim3(64, 8), 256, 0, stream>>>(QKV, QKV + (size_t)MALL * DIMN,
                                               QKV + (size_t)2 * MALL * DIMN, mask, out);
}

// Round 5
// 103.754 us; speedup vs baseline: 1.2029x; 1.0049x over previous
//
#include <hip/hip_runtime.h>
#include <hip/hip_bf16.h>

typedef __bf16 bf16;
typedef __attribute__((ext_vector_type(4))) __bf16 bf16x4;
typedef __attribute__((ext_vector_type(8))) __bf16 bf16x8;
typedef __attribute__((ext_vector_type(4))) float f32x4;

#define SEQ   4096
#define DIMN  1024
#define NHEAD 8
#define HD    128
#define MALL  4160   /* 4096 X rows + 64 Cp rows */
#define PENV  -10000.0f
#define NKT   32     /* K-tiles of 32 */

typedef const __attribute__((address_space(1))) void gvoid_t;
typedef __attribute__((address_space(3))) void lvoid_t;

// ---------------------------------------------------------------- cvt: fp32 -> bf16, X ++ Cp
__global__ __launch_bounds__(256) void cvt_cat_kernel(
    const float* __restrict__ X, const float* __restrict__ Cp, bf16* __restrict__ A) {
  int i = blockIdx.x * 256 + threadIdx.x;
  size_t base = (size_t)i * 4;
  if (base >= (size_t)MALL * DIMN) return;
  const float* src = (base < (size_t)SEQ * DIMN) ? (X + base) : (Cp + (base - (size_t)SEQ * DIMN));
  float4 v = *(const float4*)src;
  bf16x4 o;
  o[0] = (bf16)v.x; o[1] = (bf16)v.y; o[2] = (bf16)v.z; o[3] = (bf16)v.w;
  *(bf16x4*)&A[base] = o;
}

// ---------------------------------------------------------------- cvt+transpose W[k][n] -> Wt[n][k] bf16
__global__ __launch_bounds__(256) void cvt_trans_kernel(
    const float* __restrict__ W0, const float* __restrict__ W1, const float* __restrict__ W2,
    bf16* __restrict__ Wt) {
  const float* W = (blockIdx.z == 0) ? W0 : ((blockIdx.z == 1) ? W1 : W2);
  bf16* dst = Wt + (size_t)blockIdx.z * DIMN * DIMN;
  __shared__ bf16 tile[64][72];
  int k0 = blockIdx.y * 64, n0 = blockIdx.x * 64;
  int tx = threadIdx.x & 63, ty = threadIdx.x >> 6;
#pragma unroll
  for (int r = ty; r < 64; r += 4)
    tile[tx][r] = (bf16)W[(size_t)(k0 + r) * DIMN + n0 + tx];
  __syncthreads();
#pragma unroll
  for (int r = ty; r < 64; r += 4)
    dst[(size_t)(n0 + r) * DIMN + k0 + tx] = tile[r][tx];
}

// ---------------------------------------------------------------- fused QKV GEMM, 256^2 tile,
// BK=32, ring-4 LDS buffers, counted vmcnt(4) at tile boundaries (never 0 mid-loop),
// 2 fine phases per K-tile {ds_read || stage -> barrier -> lgkm -> 16 MFMA -> barrier}.
// Fragment reads are contiguous 1KB/wave at BK=32 -> bank-conflict-free without swizzle.
// z = 0:Q [m][n], 1:K [m][n], 2:V stored TRANSPOSED VT[n][m].
__global__ __launch_bounds__(512) void gemm_qkv_kernel(
    const bf16* __restrict__ A, const bf16* __restrict__ Wt,
    const float* __restrict__ bQ, const float* __restrict__ bK, const float* __restrict__ bV,
    bf16* __restrict__ QKV) {
  const int z = blockIdx.z;
  const int M = (z == 0) ? SEQ : MALL;
  const int m0 = blockIdx.y * 256;
  if (m0 >= M) return;
  const int n0 = blockIdx.x * 256;
  const bf16* Wz = Wt + (size_t)z * DIMN * DIMN;
  const float* bias = (z == 0) ? bQ : ((z == 1) ? bK : bV);
  bf16* out = QKV + (size_t)z * MALL * DIMN;

  __shared__ bf16 Ab[4][256 * 32];   // 16 KiB per buffer, ring of 4 (prefetch distance 2 tiles)
  __shared__ bf16 Bb[4][256 * 32];

  const int t = threadIdx.x;
  const int lane = t & 63, w = t >> 6;
  const int wm = w >> 2, wn = w & 3;          // 2 x 4 wave grid; per-wave output 128x64
  const int r16 = lane & 15, g4 = lane >> 4;

  f32x4 acc[8][4] = {};

  // Stage A-panel of tile k (256 rows x 32 cols, 16KB): 2 global_load_lds / thread.
  auto stageA = [&](int k) {
    int buf = k & 3;
#pragma unroll
    for (int ld = 0; ld < 2; ++ld) {
      int segBase = ld * 512 + w * 64;
      int seg = segBase + lane;
      int row = seg >> 2, cc = seg & 3;
      int gm = m0 + row; gm = (gm < M) ? gm : (M - 1);
      __builtin_amdgcn_global_load_lds(
          (gvoid_t*)(A + (size_t)gm * DIMN + k * 32 + cc * 8),
          (lvoid_t*)(&Ab[buf][segBase * 8]), 16, 0, 0);
    }
  };
  auto stageB = [&](int k) {
    int buf = k & 3;
#pragma unroll
    for (int ld = 0; ld < 2; ++ld) {
      int segBase = ld * 512 + w * 64;
      int seg = segBase + lane;
      int row = seg >> 2, cc = seg & 3;
      int gn = n0 + row;   // always < 1024
      __builtin_amdgcn_global_load_lds(
          (gvoid_t*)(Wz + (size_t)gn * DIMN + k * 32 + cc * 8),
          (lvoid_t*)(&Bb[buf][segBase * 8]), 16, 0, 0);
    }
  };

  // Prologue: tiles 0 and 1 in flight (8 loads); wait tile 0 only (counted).
  stageA(0); stageB(0); stageA(1); stageB(1);
  asm volatile("s_waitcnt vmcnt(4)" ::: "memory");
  __builtin_amdgcn_s_barrier();

  for (int k = 0; k < NKT; ++k) {
    const bf16* Abuf = &Ab[k & 3][0];
    const bf16* Bbuf = &Bb[k & 3][0];
    bf16x8 af[4], bfr[4];

    // ---------- phase 0: rows 0-127 of the wave's A panel
#pragma unroll
    for (int mf = 0; mf < 4; ++mf)
      af[mf] = *(const bf16x8*)&Abuf[(wm * 128 + mf * 16 + r16) * 32 + g4 * 8];
#pragma unroll
    for (int nf = 0; nf < 4; ++nf)
      bfr[nf] = *(const bf16x8*)&Bbuf[(wn * 64 + nf * 16 + r16) * 32 + g4 * 8];
    if (k + 2 < NKT) stageA(k + 2);
    __builtin_amdgcn_s_barrier();
    asm volatile("s_waitcnt lgkmcnt(0)" ::: "memory");
    __builtin_amdgcn_sched_barrier(0);
    __builtin_amdgcn_s_setprio(1);
#pragma unroll
    for (int mf = 0; mf < 4; ++mf)
#pragma unroll
      for (int nf = 0; nf < 4; ++nf)
        acc[mf][nf] = __builtin_amdgcn_mfma_f32_16x16x32_bf16(af[mf], bfr[nf], acc[mf][nf], 0, 0, 0);
    __builtin_amdgcn_s_setprio(0);
    __builtin_amdgcn_s_barrier();

    // ---------- phase 1: rows 128-255 (B fragments reused from registers)
    bf16x8 ag[4];
#pragma unroll
    for (int mf = 0; mf < 4; ++mf)
      ag[mf] = *(const bf16x8*)&Abuf[(wm * 128 + (4 + mf) * 16 + r16) * 32 + g4 * 8];
    if (k + 2 < NKT) stageB(k + 2);
    __builtin_amdgcn_s_barrier();
    asm volatile("s_waitcnt lgkmcnt(0)" ::: "memory");
    __builtin_amdgcn_sched_barrier(0);
    __builtin_amdgcn_s_setprio(1);
#pragma unroll
    for (int mf = 0; mf < 4; ++mf)
#pragma unroll
      for (int nf = 0; nf < 4; ++nf)
        acc[4 + mf][nf] = __builtin_amdgcn_mfma_f32_16x16x32_bf16(ag[mf], bfr[nf], acc[4 + mf][nf], 0, 0, 0);
    __builtin_amdgcn_s_setprio(0);
    // Boundary: make tile k+1 resident (counted — tile k+2's loads stay in flight).
    if (k < NKT - 2)       asm volatile("s_waitcnt vmcnt(4)" ::: "memory");
    else if (k == NKT - 2) asm volatile("s_waitcnt vmcnt(0)" ::: "memory");
    __builtin_amdgcn_s_barrier();
  }

  // ---- epilogue
  if (z == 2) {
    // V: write TRANSPOSED VT[n][m]; each thread owns 4 consecutive m -> one 8B store.
#pragma unroll
    for (int nf = 0; nf < 4; ++nf) {
      int n = n0 + wn * 64 + nf * 16 + r16;
      float bv = bias[n];
#pragma unroll
      for (int mf = 0; mf < 8; ++mf) {
        int mbase = m0 + wm * 128 + mf * 16 + g4 * 4;
        if (mbase < M) {
          bf16x4 o;
#pragma unroll
          for (int r = 0; r < 4; ++r) o[r] = (bf16)(acc[mf][nf][r] + bv);
          *(bf16x4*)&out[(size_t)n * MALL + mbase] = o;
        }
      }
    }
  } else {
#pragma unroll
    for (int nf = 0; nf < 4; ++nf) {
      int n = n0 + wn * 64 + nf * 16 + r16;
      float bv = bias[n];
#pragma unroll
      for (int mf = 0; mf < 8; ++mf) {
        int mbase = m0 + wm * 128 + mf * 16 + g4 * 4;
#pragma unroll
        for (int r = 0; r < 4; ++r) {
          int m = mbase + r;
          if (m < M) out[(size_t)m * DIMN + n] = (bf16)(acc[mf][nf][r] + bv);
        }
      }
    }
  }
}

// ---------------------------------------------------------------- key slot -> global row map (band paths)
__device__ __forceinline__ int key_row_map(int qb, int tslot) {
  if (qb <= 1) return tslot;                                    // rows 0..255
  if (qb == 63) return (tslot < 64) ? tslot : (3840 + tslot);   // block0 then blocks 61..63
  return (tslot < 64) ? tslot : ((qb - 1) * 64 + (tslot - 64)); // block0 + 3-block window
}

// ---------------------------------------------------------------- fused attention
// FLAT grid of 512 blocks with h = bid & 7: consecutive blockIdx round-robin across XCDs,
// so each XCD sees ONE head -> Q/K/VT head-slices (~3MB) fit its 4MB L2 (was 16MB thrash).
// 256 threads (4 waves x 16 queries). K staged in LDS; V read from global VT[d][row].
__global__ __launch_bounds__(256) void attn_kernel(
    const bf16* __restrict__ Q, const bf16* __restrict__ K, const bf16* __restrict__ VT,
    const float* __restrict__ mask, float* __restrict__ out) {
  const int bid = blockIdx.x;
  const int h = bid & 7, qb = bid >> 3;      // XCD-per-head swizzle
  const int t = threadIdx.x;
  const int lane = t & 63, w = t >> 6;
  const int c16 = lane & 15, g4 = lane >> 4;
  const float sl = exp2f(-(float)(h + 1));
  const float rsq = 0.088388347648318447f;  // 1/sqrt(128)

  __shared__ bf16 KV[64 * 136];  // K tile [64][136]
  __shared__ bf16 P[64][264];    // probabilities, bf16, padded

  // --- Q fragments straight from global (each wave's own 16 query rows)
  bf16x8 qf[4];
  {
    int srow = qb * 64 + w * 16 + c16;
    const bf16* qp = Q + (size_t)srow * DIMN + h * HD + g4 * 8;
#pragma unroll
    for (int ks = 0; ks < 4; ++ks) qf[ks] = *(const bf16x8*)(qp + ks * 32);
  }

  int iq[4]; float mi[4];
#pragma unroll
  for (int r = 0; r < 4; ++r) { iq[r] = qb * 64 + w * 16 + g4 * 4 + r; mi[r] = mask[iq[r]]; }

  // --- band scores: 4 chunks x 64 keys
  f32x4 sc[16] = {};
#pragma unroll
  for (int c = 0; c < 4; ++c) {
    __syncthreads();
#pragma unroll
    for (int i = 0; i < 4; ++i) {
      int idx = i * 256 + t;
      int kr = idx >> 4, dc = idx & 15;
      int gr = key_row_map(qb, c * 64 + kr);
      *(bf16x8*)&KV[kr * 136 + dc * 8] = *(const bf16x8*)&K[(size_t)gr * DIMN + h * HD + dc * 8];
    }
    __syncthreads();
#pragma unroll
    for (int ks = 0; ks < 4; ++ks)
#pragma unroll
      for (int kj = 0; kj < 4; ++kj) {
        bf16x8 bfr = *(const bf16x8*)&KV[(kj * 16 + c16) * 136 + ks * 32 + g4 * 8];
        sc[c * 4 + kj] = __builtin_amdgcn_mfma_f32_16x16x32_bf16(qf[ks], bfr, sc[c * 4 + kj], 0, 0, 0);
      }
  }

  // --- bias (distance + mask penalties) — replicates reference quirks exactly
#pragma unroll
  for (int f = 0; f < 16; ++f) {
    int tslot = f * 16 + c16;
    int jrow = key_row_map(qb, tslot);
    float mj = mask[jrow];
    int jpos = (qb == 63) ? (3840 + tslot) : jrow;   // last block: virtual key positions
    int ishift = (qb >= 2 && qb <= 62) ? 128 : 0;    // middle band: row counter from 0 quirk
#pragma unroll
    for (int r = 0; r < 4; ++r) {
      float raw = sc[f][r];
      float dist = sl * fabsf((float)(iq[r] - ishift - jpos));
      float s;
      if (qb <= 1)       s = raw * rsq - dist + (1.f - mi[r]) * PENV;
      else if (qb == 63) s = raw * rsq - dist;
      else {
        float pen = (tslot < 64) ? (1.f - mi[r]) * PENV : (1.f - mi[r] * mj) * PENV;
        s = (raw + pen) * rsq - dist;
      }
      sc[f][r] = s;
    }
  }

  // --- in-wave softmax over 256 keys (per query row), normalize, P -> LDS
#pragma unroll
  for (int r = 0; r < 4; ++r) {
    float m = -1e30f;
#pragma unroll
    for (int f = 0; f < 16; ++f) m = fmaxf(m, sc[f][r]);
#pragma unroll
    for (int d = 1; d < 16; d <<= 1) m = fmaxf(m, __shfl_xor(m, d));
    float s = 0.f;
#pragma unroll
    for (int f = 0; f < 16; ++f) { float e = __expf(sc[f][r] - m); sc[f][r] = e; s += e; }
#pragma unroll
    for (int d = 1; d < 16; d <<= 1) s += __shfl_xor(s, d);
    float inv = 1.0f / s;
#pragma unroll
    for (int f = 0; f < 16; ++f)
      P[w * 16 + g4 * 4 + r][f * 16 + c16] = (bf16)(sc[f][r] * inv);
  }

  // --- band PV: B-fragments straight from global VT (no LDS staging, no barriers)
  f32x4 ctx[8] = {};
  const bf16* vt_h = VT + (size_t)h * HD * MALL;
#pragma unroll
  for (int c = 0; c < 4; ++c) {
    int kst = key_row_map(qb, c * 64);  // chunk = 64 contiguous rows
#pragma unroll
    for (int ks = 0; ks < 2; ++ks) {
      bf16x8 pa = *(const bf16x8*)&P[w * 16 + c16][c * 64 + ks * 32 + g4 * 8];
#pragma unroll
      for (int df = 0; df < 8; ++df) {
        bf16x8 bv = *(const bf16x8*)&vt_h[(size_t)(df * 16 + c16) * MALL + kst + ks * 32 + g4 * 8];
        ctx[df] = __builtin_amdgcn_mfma_f32_16x16x32_bf16(pa, bv, ctx[df], 0, 0, 0);
      }
    }
  }

  // --- packed path (64 Cp keys, separate softmax; constants cancel so score = raw*rsq)
  __syncthreads();  // all waves done with KV (band scores) before restage
#pragma unroll
  for (int i = 0; i < 4; ++i) {
    int idx = i * 256 + t;
    int kr = idx >> 4, dc = idx & 15;
    *(bf16x8*)&KV[kr * 136 + dc * 8] = *(const bf16x8*)&K[(size_t)(SEQ + kr) * DIMN + h * HD + dc * 8];
  }
  __syncthreads();
  f32x4 sp[4] = {};
#pragma unroll
  for (int ks = 0; ks < 4; ++ks)
#pragma unroll
    for (int kj = 0; kj < 4; ++kj) {
      bf16x8 bfr = *(const bf16x8*)&KV[(kj * 16 + c16) * 136 + ks * 32 + g4 * 8];
      sp[kj] = __builtin_amdgcn_mfma_f32_16x16x32_bf16(qf[ks], bfr, sp[kj], 0, 0, 0);
    }
#pragma unroll
  for (int r = 0; r < 4; ++r) {
    float m = -1e30f;
#pragma unroll
    for (int kj = 0; kj < 4; ++kj) m = fmaxf(m, sp[kj][r] * rsq);
#pragma unroll
    for (int d = 1; d < 16; d <<= 1) m = fmaxf(m, __shfl_xor(m, d));
    float s = 0.f;
    float e[4];
#pragma unroll
    for (int kj = 0; kj < 4; ++kj) { e[kj] = __expf(sp[kj][r] * rsq - m); s += e[kj]; }
#pragma unroll
    for (int d = 1; d < 16; d <<= 1) s += __shfl_xor(s, d);
    float inv = mi[r] / s;  // packed context is pre-scaled by mask_v
#pragma unroll
    for (int kj = 0; kj < 4; ++kj)
      P[w * 16 + g4 * 4 + r][kj * 16 + c16] = (bf16)(e[kj] * inv);
  }
  // packed PV: VT rows at cols SEQ..SEQ+63
#pragma unroll
  for (int ks = 0; ks < 2; ++ks) {
    bf16x8 pa = *(const bf16x8*)&P[w * 16 + c16][ks * 32 + g4 * 8];
#pragma unroll
    for (int df = 0; df < 8; ++df) {
      bf16x8 bv = *(const bf16x8*)&vt_h[(size_t)(df * 16 + c16) * MALL + SEQ + ks * 32 + g4 * 8];
      ctx[df] = __builtin_amdgcn_mfma_f32_16x16x32_bf16(pa, bv, ctx[df], 0, 0, 0);
    }
  }

  // --- output: raw [H,S,hd] flatten; final mask uses the reshaped row quirk mask[h*512 + s/8]
#pragma unroll
  for (int df = 0; df < 8; ++df) {
    int d = df * 16 + c16;
#pragma unroll
    for (int r = 0; r < 4; ++r) {
      int s = iq[r];
      float fm = mask[h * 512 + (s >> 3)];
      out[(size_t)h * (SEQ * HD) + (size_t)s * HD + d] = ctx[df][r] * fm;
    }
  }
}

// ---------------------------------------------------------------- launch
extern "C" void kernel_launch(void* const* d_in, const int* in_sizes, int n_in,
                              void* d_out, int out_size, void* d_ws, size_t ws_size,
                              hipStream_t stream) {
  const float* X    = (const float*)d_in[0];
  const float* Cp   = (const float*)d_in[1];
  const float* mask = (const float*)d_in[2];
  const float* WQ   = (const float*)d_in[3];
  const float* bQ   = (const float*)d_in[4];
  const float* WK   = (const float*)d_in[5];
  const float* bK   = (const float*)d_in[6];
  const float* WV   = (const float*)d_in[7];
  const float* bV   = (const float*)d_in[8];
  float* out = (float*)d_out;

  bf16* Abf = (bf16*)d_ws;                              // [4160][1024]
  bf16* Wt  = Abf + (size_t)MALL * DIMN;                // 3 x [1024][1024] (transposed)
  bf16* QKV = Wt + (size_t)3 * DIMN * DIMN;             // q[4160][1024], k[4160][1024], VT[1024][4160]

  int nCvt = (MALL * DIMN / 4 + 255) / 256;
  cvt_cat_kernel<<<nCvt, 256, 0, stream>>>(X, Cp, Abf);
  cvt_trans_kernel<<<dim3(16, 16, 3), 256, 0, stream>>>(WQ, WK, WV, Wt);
  gemm_qkv_kernel<<<dim3(4, 17, 3), 512, 0, stream>>>(Abf, Wt, bQ, bK, bV, QKV);
  attn_kernel<<<512, 256, 0, stream>>>(QKV, QKV + (size_t)MALL * DIMN,
                                       QKV + (size_t)2 * MALL * DIMN, mask, out);
}

// Round 6
// 93.430 us; speedup vs baseline: 1.3358x; 1.1105x over previous
//
#include <hip/hip_runtime.h>
#include <hip/hip_bf16.h>

typedef __bf16 bf16;
typedef __attribute__((ext_vector_type(4))) __bf16 bf16x4;
typedef __attribute__((ext_vector_type(8))) __bf16 bf16x8;
typedef __attribute__((ext_vector_type(4))) float f32x4;

#define SEQ   4096
#define DIMN  1024
#define NHEAD 8
#define HD    128
#define MALL  4160   /* 4096 X rows + 64 Cp rows */
#define PENV  -10000.0f
#define NT    16     /* K-tiles of 64 */

typedef const __attribute__((address_space(1))) void gvoid_t;
typedef __attribute__((address_space(3))) void lvoid_t;

// ---------------------------------------------------------------- cvt: fp32 -> bf16, X ++ Cp
__global__ __launch_bounds__(256) void cvt_cat_kernel(
    const float* __restrict__ X, const float* __restrict__ Cp, bf16* __restrict__ A) {
  int i = blockIdx.x * 256 + threadIdx.x;
  size_t base = (size_t)i * 4;
  if (base >= (size_t)MALL * DIMN) return;
  const float* src = (base < (size_t)SEQ * DIMN) ? (X + base) : (Cp + (base - (size_t)SEQ * DIMN));
  float4 v = *(const float4*)src;
  bf16x4 o;
  o[0] = (bf16)v.x; o[1] = (bf16)v.y; o[2] = (bf16)v.z; o[3] = (bf16)v.w;
  *(bf16x4*)&A[base] = o;
}

// ---------------------------------------------------------------- cvt+transpose W[k][n] -> Wt[n][k] bf16
__global__ __launch_bounds__(256) void cvt_trans_kernel(
    const float* __restrict__ W0, const float* __restrict__ W1, const float* __restrict__ W2,
    bf16* __restrict__ Wt) {
  const float* W = (blockIdx.z == 0) ? W0 : ((blockIdx.z == 1) ? W1 : W2);
  bf16* dst = Wt + (size_t)blockIdx.z * DIMN * DIMN;
  __shared__ bf16 tile[64][72];
  int k0 = blockIdx.y * 64, n0 = blockIdx.x * 64;
  int tx = threadIdx.x & 63, ty = threadIdx.x >> 6;
#pragma unroll
  for (int r = ty; r < 64; r += 4)
    tile[tx][r] = (bf16)W[(size_t)(k0 + r) * DIMN + n0 + tx];
  __syncthreads();
#pragma unroll
  for (int r = ty; r < 64; r += 4)
    dst[(size_t)(n0 + r) * DIMN + k0 + tx] = tile[r][tx];
}

// ---------------------------------------------------------------- fused QKV GEMM, 256^2 tile,
// BK=64, dbuf-2 LDS, XOR chunk swizzle (source+read), 4 pipelined sub-phases per tile:
// frag ds_reads issued one sub-phase AHEAD of the MFMA cluster that consumes them, so the
// LDS pipe runs under the MFMA pipe (was: lgkmcnt(0)-before-every-MFMA lockstep).
// One vmcnt(0)+barrier per K-tile; stages issued ~1 tile before their wait.
// z = 0:Q [m][n], 1:K [m][n], 2:V stored TRANSPOSED VT[n][m].
__global__ __launch_bounds__(512) void gemm_qkv_kernel(
    const bf16* __restrict__ A, const bf16* __restrict__ Wt,
    const float* __restrict__ bQ, const float* __restrict__ bK, const float* __restrict__ bV,
    bf16* __restrict__ QKV) {
  const int z = blockIdx.z;
  const int M = (z == 0) ? SEQ : MALL;
  const int m0 = blockIdx.y * 256;
  if (m0 >= M) return;
  const int n0 = blockIdx.x * 256;
  const bf16* Wz = Wt + (size_t)z * DIMN * DIMN;
  const float* bias = (z == 0) ? bQ : ((z == 1) ? bK : bV);
  bf16* out = QKV + (size_t)z * MALL * DIMN;

  __shared__ bf16 Ab[2][256 * 64];   // 32 KiB each; linear rows of 64, chunk-XOR-swizzled contents
  __shared__ bf16 Bb[2][256 * 64];

  const int t = threadIdx.x;
  const int lane = t & 63, w = t >> 6;
  const int wm = w >> 2, wn = w & 3;          // 2 x 4 wave grid; per-wave output 128x64
  const int r16 = lane & 15, g4 = lane >> 4;

  f32x4 acc[8][4] = {};

  // Stage A/B panel of tile k (256x64, 32KB each): 4 gloads/thread each.
  auto stageA = [&](int k) {
    int b = k & 1;
#pragma unroll
    for (int i = 0; i < 4; ++i) {
      int segBase = i * 512 + w * 64;
      int seg = segBase + lane;
      int row = seg >> 3;
      int cc = (seg & 7) ^ (row & 7);       // source-side swizzle
      int gm = m0 + row; gm = (gm < M) ? gm : (M - 1);
      __builtin_amdgcn_global_load_lds(
          (gvoid_t*)(A + (size_t)gm * DIMN + k * 64 + cc * 8),
          (lvoid_t*)(&Ab[b][segBase * 8]), 16, 0, 0);
    }
  };
  auto stageB = [&](int k) {
    int b = k & 1;
#pragma unroll
    for (int i = 0; i < 4; ++i) {
      int segBase = i * 512 + w * 64;
      int seg = segBase + lane;
      int row = seg >> 3;
      int cc = (seg & 7) ^ (row & 7);
      int gn = n0 + row;   // always < 1024
      __builtin_amdgcn_global_load_lds(
          (gvoid_t*)(Wz + (size_t)gn * DIMN + k * 64 + cc * 8),
          (lvoid_t*)(&Bb[b][segBase * 8]), 16, 0, 0);
    }
  };

  // LDS fragment read helpers (read-side swizzle matches source-side).
  auto rdA = [&](const bf16* Ax, int mf, int kk) -> bf16x8 {
    int row = wm * 128 + mf * 16 + r16;
    return *(const bf16x8*)&Ax[row * 64 + (((kk * 4 + g4) ^ (row & 7)) * 8)];
  };
  auto rdB = [&](const bf16* Bx, int nf, int kk) -> bf16x8 {
    int row = wn * 64 + nf * 16 + r16;
    return *(const bf16x8*)&Bx[row * 64 + (((kk * 4 + g4) ^ (row & 7)) * 8)];
  };

  // Prologue: tile 0 resident before first reads.
  stageA(0); stageB(0);
  asm volatile("s_waitcnt vmcnt(0)" ::: "memory");
  __builtin_amdgcn_s_barrier();

  for (int k = 0; k < NT; ++k) {
    const bf16* Ax = &Ab[k & 1][0];
    const bf16* Bx = &Bb[k & 1][0];
    bf16x8 aL[4], aH[4], bL[4];

    // F0 + F1 frag reads (kk0), then issue next tile's A stage.
#pragma unroll
    for (int mf = 0; mf < 4; ++mf) aL[mf] = rdA(Ax, mf, 0);
#pragma unroll
    for (int nf = 0; nf < 4; ++nf) bL[nf] = rdB(Bx, nf, 0);
#pragma unroll
    for (int mf = 0; mf < 4; ++mf) aH[mf] = rdA(Ax, 4 + mf, 0);
    if (k + 1 < NT) stageA(k + 1);
    __builtin_amdgcn_sched_barrier(0);

    // MFMA F0 (acc rows 0-3, kk0) — aH reads + stage still in flight above us.
    __builtin_amdgcn_s_setprio(1);
#pragma unroll
    for (int mf = 0; mf < 4; ++mf)
#pragma unroll
      for (int nf = 0; nf < 4; ++nf)
        acc[mf][nf] = __builtin_amdgcn_mfma_f32_16x16x32_bf16(aL[mf], bL[nf], acc[mf][nf], 0, 0, 0);
    __builtin_amdgcn_s_setprio(0);

    // F2 frag reads (kk1 lo + B kk1), then B stage.
    bf16x8 aL2[4], bL2[4];
#pragma unroll
    for (int mf = 0; mf < 4; ++mf) aL2[mf] = rdA(Ax, mf, 1);
#pragma unroll
    for (int nf = 0; nf < 4; ++nf) bL2[nf] = rdB(Bx, nf, 1);
    if (k + 1 < NT) stageB(k + 1);
    __builtin_amdgcn_sched_barrier(0);

    // MFMA F1 (acc rows 4-7, kk0; bL reused from registers).
    __builtin_amdgcn_s_setprio(1);
#pragma unroll
    for (int mf = 0; mf < 4; ++mf)
#pragma unroll
      for (int nf = 0; nf < 4; ++nf)
        acc[4 + mf][nf] = __builtin_amdgcn_mfma_f32_16x16x32_bf16(aH[mf], bL[nf], acc[4 + mf][nf], 0, 0, 0);
    __builtin_amdgcn_s_setprio(0);

    // F3 frag reads (kk1 hi).
#pragma unroll
    for (int mf = 0; mf < 4; ++mf) aH[mf] = rdA(Ax, 4 + mf, 1);

    // MFMA F2 (acc rows 0-3, kk1).
    __builtin_amdgcn_s_setprio(1);
#pragma unroll
    for (int mf = 0; mf < 4; ++mf)
#pragma unroll
      for (int nf = 0; nf < 4; ++nf)
        acc[mf][nf] = __builtin_amdgcn_mfma_f32_16x16x32_bf16(aL2[mf], bL2[nf], acc[mf][nf], 0, 0, 0);

    // MFMA F3 (acc rows 4-7, kk1).
#pragma unroll
    for (int mf = 0; mf < 4; ++mf)
#pragma unroll
      for (int nf = 0; nf < 4; ++nf)
        acc[4 + mf][nf] = __builtin_amdgcn_mfma_f32_16x16x32_bf16(aH[mf], bL2[nf], acc[4 + mf][nf], 0, 0, 0);
    __builtin_amdgcn_s_setprio(0);

    if (k + 1 < NT) {
      asm volatile("s_waitcnt vmcnt(0)" ::: "memory");  // tile k+1 stages landed (issued ~1 tile ago)
      __builtin_amdgcn_s_barrier();                     // all waves done reading buf k&1 + stages visible
    }
  }

  // ---- epilogue
  if (z == 2) {
    // V: write TRANSPOSED VT[n][m]; each thread owns 4 consecutive m -> one 8B store.
#pragma unroll
    for (int nf = 0; nf < 4; ++nf) {
      int n = n0 + wn * 64 + nf * 16 + r16;
      float bv = bias[n];
#pragma unroll
      for (int mf = 0; mf < 8; ++mf) {
        int mbase = m0 + wm * 128 + mf * 16 + g4 * 4;
        if (mbase < M) {
          bf16x4 o;
#pragma unroll
          for (int r = 0; r < 4; ++r) o[r] = (bf16)(acc[mf][nf][r] + bv);
          *(bf16x4*)&out[(size_t)n * MALL + mbase] = o;
        }
      }
    }
  } else {
#pragma unroll
    for (int nf = 0; nf < 4; ++nf) {
      int n = n0 + wn * 64 + nf * 16 + r16;
      float bv = bias[n];
#pragma unroll
      for (int mf = 0; mf < 8; ++mf) {
        int mbase = m0 + wm * 128 + mf * 16 + g4 * 4;
#pragma unroll
        for (int r = 0; r < 4; ++r) {
          int m = mbase + r;
          if (m < M) out[(size_t)m * DIMN + n] = (bf16)(acc[mf][nf][r] + bv);
        }
      }
    }
  }
}

// ---------------------------------------------------------------- key slot -> global row map (band paths)
__device__ __forceinline__ int key_row_map(int qb, int tslot) {
  if (qb <= 1) return tslot;                                    // rows 0..255
  if (qb == 63) return (tslot < 64) ? tslot : (3840 + tslot);   // block0 then blocks 61..63
  return (tslot < 64) ? tslot : ((qb - 1) * 64 + (tslot - 64)); // block0 + 3-block window
}

// ---------------------------------------------------------------- fused attention
// Flat 512-block grid, h=bid&7. 256 threads (4 waves x 16 queries).
// K staged via global_load_lds into a 2-deep ring with chunk-XOR swizzle and COUNTED
// vmcnt(4): stage of chunk c+1 flies under chunk c's MFMA (5 chunks: 4 band + packed).
// V read directly from global VT[d][row].
__global__ __launch_bounds__(256) void attn_kernel(
    const bf16* __restrict__ Q, const bf16* __restrict__ K, const bf16* __restrict__ VT,
    const float* __restrict__ mask, float* __restrict__ out) {
  const int bid = blockIdx.x;
  const int h = bid & 7, qb = bid >> 3;
  const int t = threadIdx.x;
  const int lane = t & 63, w = t >> 6;
  const int c16 = lane & 15, g4 = lane >> 4;
  const float sl = exp2f(-(float)(h + 1));
  const float rsq = 0.088388347648318447f;  // 1/sqrt(128)

  __shared__ bf16 KB[2][64 * 128];  // 16 KiB ring buffers, linear, chunk-XOR-swizzled contents
  __shared__ bf16 P[64][264];       // probabilities, bf16, padded

  // --- Q fragments + mask loads issued first (oldest in the vmcnt queue)
  bf16x8 qf[4];
  {
    int srow = qb * 64 + w * 16 + c16;
    const bf16* qp = Q + (size_t)srow * DIMN + h * HD + g4 * 8;
#pragma unroll
    for (int ks = 0; ks < 4; ++ks) qf[ks] = *(const bf16x8*)(qp + ks * 32);
  }
  int iq[4]; float mi[4];
#pragma unroll
  for (int r = 0; r < 4; ++r) { iq[r] = qb * 64 + w * 16 + g4 * 4 + r; mi[r] = mask[iq[r]]; }

  // Stage K chunk c (64 rows x 128 cols, 16KB = 4 gloads/thread) into KB[c&1].
  auto stageK = [&](int c) {
#pragma unroll
    for (int i = 0; i < 4; ++i) {
      int segBase = i * 256 + w * 64;
      int seg = segBase + lane;
      int kr = seg >> 4;
      int cc = (seg & 15) ^ (kr & 7);   // source-side swizzle
      int gr = (c == 4) ? (SEQ + kr) : key_row_map(qb, c * 64 + kr);
      __builtin_amdgcn_global_load_lds(
          (gvoid_t*)(K + (size_t)gr * DIMN + h * HD + cc * 8),
          (lvoid_t*)(&KB[c & 1][segBase * 8]), 16, 0, 0);
    }
  };

  f32x4 sc[16] = {};
  f32x4 sp[4] = {};

  stageK(0);
#pragma unroll
  for (int c = 0; c < 5; ++c) {
    if (c < 4) {
      stageK(c + 1);
      asm volatile("s_waitcnt vmcnt(4)" ::: "memory");  // chunk c resident; c+1's 4 still in flight
    } else {
      asm volatile("s_waitcnt vmcnt(0)" ::: "memory");
    }
    __builtin_amdgcn_s_barrier();   // all waves' chunk-c stages visible
    const bf16* Kx = &KB[c & 1][0];
#pragma unroll
    for (int ks = 0; ks < 4; ++ks)
#pragma unroll
      for (int kj = 0; kj < 4; ++kj) {
        int row = kj * 16 + c16;
        bf16x8 bfr = *(const bf16x8*)&Kx[row * 128 + (((ks * 4 + g4) ^ (row & 7)) * 8)];
        if (c < 4)
          sc[c * 4 + kj] = __builtin_amdgcn_mfma_f32_16x16x32_bf16(qf[ks], bfr, sc[c * 4 + kj], 0, 0, 0);
        else
          sp[kj] = __builtin_amdgcn_mfma_f32_16x16x32_bf16(qf[ks], bfr, sp[kj], 0, 0, 0);
      }
    __builtin_amdgcn_s_barrier();   // all waves done reading KB[c&1] before stage(c+2) overwrites
  }

  // --- bias (distance + mask penalties) — replicates reference quirks exactly
#pragma unroll
  for (int f = 0; f < 16; ++f) {
    int tslot = f * 16 + c16;
    int jrow = key_row_map(qb, tslot);
    float mj = mask[jrow];
    int jpos = (qb == 63) ? (3840 + tslot) : jrow;   // last block: virtual key positions
    int ishift = (qb >= 2 && qb <= 62) ? 128 : 0;    // middle band: row counter from 0 quirk
#pragma unroll
    for (int r = 0; r < 4; ++r) {
      float raw = sc[f][r];
      float dist = sl * fabsf((float)(iq[r] - ishift - jpos));
      float s;
      if (qb <= 1)       s = raw * rsq - dist + (1.f - mi[r]) * PENV;
      else if (qb == 63) s = raw * rsq - dist;
      else {
        float pen = (tslot < 64) ? (1.f - mi[r]) * PENV : (1.f - mi[r] * mj) * PENV;
        s = (raw + pen) * rsq - dist;
      }
      sc[f][r] = s;
    }
  }

  // --- in-wave softmax over 256 keys (per query row), normalize, P -> LDS (wave-private rows)
#pragma unroll
  for (int r = 0; r < 4; ++r) {
    float m = -1e30f;
#pragma unroll
    for (int f = 0; f < 16; ++f) m = fmaxf(m, sc[f][r]);
#pragma unroll
    for (int d = 1; d < 16; d <<= 1) m = fmaxf(m, __shfl_xor(m, d));
    float s = 0.f;
#pragma unroll
    for (int f = 0; f < 16; ++f) { float e = __expf(sc[f][r] - m); sc[f][r] = e; s += e; }
#pragma unroll
    for (int d = 1; d < 16; d <<= 1) s += __shfl_xor(s, d);
    float inv = 1.0f / s;
#pragma unroll
    for (int f = 0; f < 16; ++f)
      P[w * 16 + g4 * 4 + r][f * 16 + c16] = (bf16)(sc[f][r] * inv);
  }

  // --- band PV: B-fragments straight from global VT (no LDS staging, no barriers)
  f32x4 ctx[8] = {};
  const bf16* vt_h = VT + (size_t)h * HD * MALL;
#pragma unroll
  for (int c = 0; c < 4; ++c) {
    int kst = key_row_map(qb, c * 64);  // chunk = 64 contiguous rows
#pragma unroll
    for (int ks = 0; ks < 2; ++ks) {
      bf16x8 pa = *(const bf16x8*)&P[w * 16 + c16][c * 64 + ks * 32 + g4 * 8];
#pragma unroll
      for (int df = 0; df < 8; ++df) {
        bf16x8 bv = *(const bf16x8*)&vt_h[(size_t)(df * 16 + c16) * MALL + kst + ks * 32 + g4 * 8];
        ctx[df] = __builtin_amdgcn_mfma_f32_16x16x32_bf16(pa, bv, ctx[df], 0, 0, 0);
      }
    }
  }

  // --- packed softmax (constants cancel; score = raw*rsq), P rows are wave-private
#pragma unroll
  for (int r = 0; r < 4; ++r) {
    float m = -1e30f;
#pragma unroll
    for (int kj = 0; kj < 4; ++kj) m = fmaxf(m, sp[kj][r] * rsq);
#pragma unroll
    for (int d = 1; d < 16; d <<= 1) m = fmaxf(m, __shfl_xor(m, d));
    float s = 0.f;
    float e[4];
#pragma unroll
    for (int kj = 0; kj < 4; ++kj) { e[kj] = __expf(sp[kj][r] * rsq - m); s += e[kj]; }
#pragma unroll
    for (int d = 1; d < 16; d <<= 1) s += __shfl_xor(s, d);
    float inv = mi[r] / s;  // packed context is pre-scaled by mask_v
#pragma unroll
    for (int kj = 0; kj < 4; ++kj)
      P[w * 16 + g4 * 4 + r][kj * 16 + c16] = (bf16)(e[kj] * inv);
  }
  // packed PV: VT rows at cols SEQ..SEQ+63
#pragma unroll
  for (int ks = 0; ks < 2; ++ks) {
    bf16x8 pa = *(const bf16x8*)&P[w * 16 + c16][ks * 32 + g4 * 8];
#pragma unroll
    for (int df = 0; df < 8; ++df) {
      bf16x8 bv = *(const bf16x8*)&vt_h[(size_t)(df * 16 + c16) * MALL + SEQ + ks * 32 + g4 * 8];
      ctx[df] = __builtin_amdgcn_mfma_f32_16x16x32_bf16(pa, bv, ctx[df], 0, 0, 0);
    }
  }

  // --- output: raw [H,S,hd] flatten; final mask uses the reshaped row quirk mask[h*512 + s/8]
#pragma unroll
  for (int df = 0; df < 8; ++df) {
    int d = df * 16 + c16;
#pragma unroll
    for (int r = 0; r < 4; ++r) {
      int s = iq[r];
      float fm = mask[h * 512 + (s >> 3)];
      out[(size_t)h * (SEQ * HD) + (size_t)s * HD + d] = ctx[df][r] * fm;
    }
  }
}

// ---------------------------------------------------------------- launch
extern "C" void kernel_launch(void* const* d_in, const int* in_sizes, int n_in,
                              void* d_out, int out_size, void* d_ws, size_t ws_size,
                              hipStream_t stream) {
  const float* X    = (const float*)d_in[0];
  const float* Cp   = (const float*)d_in[1];
  const float* mask = (const float*)d_in[2];
  const float* WQ   = (const float*)d_in[3];
  const float* bQ   = (const float*)d_in[4];
  const float* WK   = (const float*)d_in[5];
  const float* bK   = (const float*)d_in[6];
  const float* WV   = (const float*)d_in[7];
  const float* bV   = (const float*)d_in[8];
  float* out = (float*)d_out;

  bf16* Abf = (bf16*)d_ws;                              // [4160][1024]
  bf16* Wt  = Abf + (size_t)MALL * DIMN;                // 3 x [1024][1024] (transposed)
  bf16* QKV = Wt + (size_t)3 * DIMN * DIMN;             // q[4160][1024], k[4160][1024], VT[1024][4160]

  int nCvt = (MALL * DIMN / 4 + 255) / 256;
  cvt_cat_kernel<<<nCvt, 256, 0, stream>>>(X, Cp, Abf);
  cvt_trans_kernel<<<dim3(16, 16, 3), 256, 0, stream>>>(WQ, WK, WV, Wt);
  gemm_qkv_kernel<<<dim3(4, 17, 3), 512, 0, stream>>>(Abf, Wt, bQ, bK, bV, QKV);
  attn_kernel<<<512, 256, 0, stream>>>(QKV, QKV + (size_t)MALL * DIMN,
                                       QKV + (size_t)2 * MALL * DIMN, mask, out);
}